// Round 3
// baseline (917.452 us; speedup 1.0000x reference)
//
#include <hip/hip_runtime.h>

#define RH 32
#define RT 2048
#define RC 10

// LDS float offsets
#define XR0   0       // batch-A x ring: 4 slots x 256 floats (8 steps each)
#define XR1   1024    // batch-B x ring
#define H1O   2048    // h1[2][32]
#define H2O   2112    // h2[2][32]
#define TRO   2176    // trash[32]
#define LDSF  2208

// tanh(x) = 1 - 2/(exp(2x)+1); saturates correctly at +/-inf.
__device__ __forceinline__ float fast_tanh(float x) {
    float e = __builtin_amdgcn_exp2f(x * 2.88539008177792681472f); // 2*log2(e)
    return fmaf(-2.0f, __builtin_amdgcn_rcpf(e + 1.0f), 1.0f);
}

__global__ __launch_bounds__(64) void rnn2_kernel(
    const float* __restrict__ x,
    const float* __restrict__ W_ih0, const float* __restrict__ W_hh0,
    const float* __restrict__ b_ih0, const float* __restrict__ b_hh0,
    const float* __restrict__ W_ih1, const float* __restrict__ W_hh1,
    const float* __restrict__ b_ih1, const float* __restrict__ b_hh1,
    const float* __restrict__ fc_w, const float* __restrict__ fc_b,
    float* __restrict__ out)
{
    __shared__ float lds[LDSF];
    const int blk  = blockIdx.x;      // 256 blocks, 1 wave each, 2 batches each
    const int lane = threadIdx.x;
    const int g    = lane >> 5;       // batch select within block
    const int j    = lane & 31;       // output row

    const float* xA = x + (size_t)(2 * blk) * RT * RH;
    const float* xB = xA + (size_t)RT * RH;

    // Full weight rows in registers (replicated across the two halves).
    float w0[RH], wh0[RH], w1[RH], wh1[RH];
#pragma unroll
    for (int q = 0; q < 8; ++q) {
        float4 a = *(const float4*)&W_ih0[j * RH + q * 4];
        float4 b = *(const float4*)&W_hh0[j * RH + q * 4];
        float4 c = *(const float4*)&W_ih1[j * RH + q * 4];
        float4 d = *(const float4*)&W_hh1[j * RH + q * 4];
        w0 [q*4+0]=a.x; w0 [q*4+1]=a.y; w0 [q*4+2]=a.z; w0 [q*4+3]=a.w;
        wh0[q*4+0]=b.x; wh0[q*4+1]=b.y; wh0[q*4+2]=b.z; wh0[q*4+3]=b.w;
        w1 [q*4+0]=c.x; w1 [q*4+1]=c.y; w1 [q*4+2]=c.z; w1 [q*4+3]=c.w;
        wh1[q*4+0]=d.x; wh1[q*4+1]=d.y; wh1[q*4+2]=d.z; wh1[q*4+3]=d.w;
    }
    const float bias1 = b_ih0[j] + b_hh0[j];
    const float bias2 = b_ih1[j] + b_hh1[j];

    lds[H1O + lane] = 0.0f;   // covers both batches' h1
    lds[H2O + lane] = 0.0f;
    __syncthreads();

    const int xbase = g * 1024;                 // XR0 / XR1
    float* const h1w = &lds[H1O + g * 32 + j];
    float* const h2w = &lds[H2O + g * 32 + j];
    float* const trw = &lds[TRO + j];

    // Stage one 8-step chunk (1 KiB) per batch, direct global->LDS.
#define STAGE2(c) do {                                                        \
    __builtin_amdgcn_global_load_lds(                                         \
        (const __attribute__((address_space(1))) void*)(xA + (c) * 256 + lane * 4), \
        (__attribute__((address_space(3))) void*)&lds[XR0 + ((c) & 3) * 256], \
        16, 0, 0);                                                            \
    __builtin_amdgcn_global_load_lds(                                         \
        (const __attribute__((address_space(1))) void*)(xB + (c) * 256 + lane * 4), \
        (__attribute__((address_space(3))) void*)&lds[XR1 + ((c) & 3) * 256], \
        16, 0, 0);                                                            \
} while (0)

    // One time-step for this lane's batch: layer1 at t, layer2 at t-1.
    // All inputs (h1(t-1), h2(t-2)) are pre-step snapshots; writes at end.
#define STEP(SB, S, H1D, H2D) do {                                           \
    const float4* xp = (const float4*)&lds[(SB) + (S) * 32];                 \
    const float4* ap = (const float4*)&lds[H1O + g * 32];                    \
    const float4* bp = (const float4*)&lds[H2O + g * 32];                    \
    float ax0=0.f, ax1=0.f, ah0=0.f, ah1=0.f;                                \
    float ba0=0.f, ba1=0.f, bb0=0.f, bb1=0.f;                                \
    _Pragma("unroll")                                                        \
    for (int q = 0; q < 8; ++q) {                                            \
        float4 xv = xp[q]; float4 av = ap[q]; float4 bv = bp[q];             \
        ax0 = fmaf(w0 [q*4+0], xv.x, ax0);                                   \
        ax1 = fmaf(w0 [q*4+1], xv.y, ax1);                                   \
        ah0 = fmaf(wh0[q*4+0], av.x, ah0);                                   \
        ah1 = fmaf(wh0[q*4+1], av.y, ah1);                                   \
        ba0 = fmaf(w1 [q*4+0], av.x, ba0);                                   \
        ba1 = fmaf(w1 [q*4+1], av.y, ba1);                                   \
        bb0 = fmaf(wh1[q*4+0], bv.x, bb0);                                   \
        bb1 = fmaf(wh1[q*4+1], bv.y, bb1);                                   \
        ax0 = fmaf(w0 [q*4+2], xv.z, ax0);                                   \
        ax1 = fmaf(w0 [q*4+3], xv.w, ax1);                                   \
        ah0 = fmaf(wh0[q*4+2], av.z, ah0);                                   \
        ah1 = fmaf(wh0[q*4+3], av.w, ah1);                                   \
        ba0 = fmaf(w1 [q*4+2], av.z, ba0);                                   \
        ba1 = fmaf(w1 [q*4+3], av.w, ba1);                                   \
        bb0 = fmaf(wh1[q*4+2], bv.z, bb0);                                   \
        bb1 = fmaf(wh1[q*4+3], bv.w, bb1);                                   \
    }                                                                        \
    float a1 = (ax0 + ax1) + (ah0 + ah1) + bias1;                            \
    float a2 = (ba0 + ba1) + (bb0 + bb1) + bias2;                            \
    *(H1D) = fast_tanh(a1);                                                  \
    *(H2D) = fast_tanh(a2);                                                  \
    __asm__ volatile("" ::: "memory");                                       \
} while (0)

    STAGE2(0); STAGE2(1); STAGE2(2);
    __asm__ volatile("s_waitcnt vmcnt(4)" ::: "memory");

    {   // chunk 0 (slot 0): t = 0..7; t=0's layer-2 output (h2(-1)) -> trash
        const int sb = xbase;
        STEP(sb, 0, h1w, trw);
        STEP(sb, 1, h1w, h2w); STEP(sb, 2, h1w, h2w); STEP(sb, 3, h1w, h2w);
        STEP(sb, 4, h1w, h2w); STEP(sb, 5, h1w, h2w); STEP(sb, 6, h1w, h2w);
        STEP(sb, 7, h1w, h2w);
    }
    for (int c = 1; c <= 253; ++c) {
        STAGE2(c + 2);                       // slot (c+2)&3, never the live one
        __asm__ volatile("s_waitcnt vmcnt(4)" ::: "memory");
        const int sb = xbase + (c & 3) * 256;
        STEP(sb, 0, h1w, h2w); STEP(sb, 1, h1w, h2w); STEP(sb, 2, h1w, h2w);
        STEP(sb, 3, h1w, h2w); STEP(sb, 4, h1w, h2w); STEP(sb, 5, h1w, h2w);
        STEP(sb, 6, h1w, h2w); STEP(sb, 7, h1w, h2w);
    }
    {   // chunk 254 (slot 2)
        __asm__ volatile("s_waitcnt vmcnt(2)" ::: "memory");
        const int sb = xbase + 2 * 256;
        STEP(sb, 0, h1w, h2w); STEP(sb, 1, h1w, h2w); STEP(sb, 2, h1w, h2w);
        STEP(sb, 3, h1w, h2w); STEP(sb, 4, h1w, h2w); STEP(sb, 5, h1w, h2w);
        STEP(sb, 6, h1w, h2w); STEP(sb, 7, h1w, h2w);
    }
    {   // chunk 255 (slot 3)
        __asm__ volatile("s_waitcnt vmcnt(0)" ::: "memory");
        const int sb = xbase + 3 * 256;
        STEP(sb, 0, h1w, h2w); STEP(sb, 1, h1w, h2w); STEP(sb, 2, h1w, h2w);
        STEP(sb, 3, h1w, h2w); STEP(sb, 4, h1w, h2w); STEP(sb, 5, h1w, h2w);
        STEP(sb, 6, h1w, h2w); STEP(sb, 7, h1w, h2w);
    }
    // t = 2048: layer2 finishes h2(2047); layer1 result (stale x) -> trash
    STEP(xbase, 0, trw, h2w);
#undef STEP
#undef STAGE2

    // FC epilogue: logits for both batches of this block.
    if (j < RC) {
        float s = fc_b[j];
#pragma unroll
        for (int k = 0; k < RH; ++k)
            s = fmaf(fc_w[j * RH + k], lds[H2O + g * 32 + k], s);
        out[(size_t)(2 * blk + g) * RC + j] = s;
    }
}

extern "C" void kernel_launch(void* const* d_in, const int* in_sizes, int n_in,
                              void* d_out, int out_size, void* d_ws, size_t ws_size,
                              hipStream_t stream) {
    const float* x     = (const float*)d_in[0];
    const float* W_ih0 = (const float*)d_in[1];
    const float* W_hh0 = (const float*)d_in[2];
    const float* b_ih0 = (const float*)d_in[3];
    const float* b_hh0 = (const float*)d_in[4];
    const float* W_ih1 = (const float*)d_in[5];
    const float* W_hh1 = (const float*)d_in[6];
    const float* b_ih1 = (const float*)d_in[7];
    const float* b_hh1 = (const float*)d_in[8];
    const float* fc_w  = (const float*)d_in[9];
    const float* fc_b  = (const float*)d_in[10];
    float* out = (float*)d_out;

    rnn2_kernel<<<256, 64, 0, stream>>>(x, W_ih0, W_hh0, b_ih0, b_hh0,
                                        W_ih1, W_hh1, b_ih1, b_hh1,
                                        fc_w, fc_b, out);
}

// Round 4
// 863.710 us; speedup vs baseline: 1.0622x; 1.0622x over previous
//
#include <hip/hip_runtime.h>

#define RH 32
#define RT 2048
#define RC 10

typedef __attribute__((ext_vector_type(8))) short bf16x8;
typedef __attribute__((ext_vector_type(4))) float f32x4;

#define MFMA(a,b,c) __builtin_amdgcn_mfma_f32_16x16x32_bf16((a),(b),(c),0,0,0)

__device__ __forceinline__ unsigned short f2bf(float f) {
    unsigned u = __float_as_uint(f);
    u += 0x7fffu + ((u >> 16) & 1u);      // RNE
    return (unsigned short)(u >> 16);
}
__device__ __forceinline__ float bf2f(unsigned short h) {
    return __uint_as_float(((unsigned)h) << 16);
}
// tanh(x) = 1 - 2/(exp(2x)+1); saturates correctly at +/-inf.
__device__ __forceinline__ float fast_tanh(float x) {
    float e = __builtin_amdgcn_exp2f(x * 2.88539008177792681472f);
    return fmaf(-2.0f, __builtin_amdgcn_rcpf(e + 1.0f), 1.0f);
}

// A-frag for W rows [base, base+16): lane(n,g) holds W[base+n][k], k = 4g+(e&3)+16*(e>>2)
__device__ __forceinline__ void load_wfrag(const float* __restrict__ W, int base,
                                           int n, int g, bf16x8& hi, bf16x8& lo) {
#pragma unroll
    for (int e = 0; e < 8; ++e) {
        int k = 4*g + (e & 3) + 16*(e >> 2);
        float w = W[(base + n)*RH + k];
        unsigned short hb = f2bf(w);
        hi[e] = (short)hb;
        lo[e] = (short)f2bf(w - bf2f(hb));
    }
}

__global__ __launch_bounds__(128) void rnn2_mfma_kernel(
    const float* __restrict__ x,
    const float* __restrict__ W_ih0, const float* __restrict__ W_hh0,
    const float* __restrict__ b_ih0, const float* __restrict__ b_hh0,
    const float* __restrict__ W_ih1, const float* __restrict__ W_hh1,
    const float* __restrict__ b_ih1, const float* __restrict__ b_hh1,
    const float* __restrict__ fc_w, const float* __restrict__ fc_b,
    float* __restrict__ out)
{
    __shared__ __align__(16) short hslab[2][2][64][8]; // [slot][hi/lo][lane][frag bf16]
    __shared__ __align__(16) float h2fin[16][RH];

    const int tid = threadIdx.x;
    const int wv  = tid >> 6;        // wave 0: layer1 @ t, wave 1: layer2 @ t-1
    const int ln  = tid & 63;
    const int n   = ln & 15;         // batch column within 16-batch tile
    const int g   = ln >> 4;         // k/row 4-group

    // Weight frags (per wave: its own 2 matrices), hi/lo bf16 split.
    bf16x8 WIhi0, WIlo0, WIhi1, WIlo1;   // "input" operand weights (x for L1, h1 for L2)
    bf16x8 WHhi0, WHlo0, WHhi1, WHlo1;   // recurrent weights
    bf16x8 hsh = {0,0,0,0,0,0,0,0};      // own recurrent state frag hi (h1 / h2)
    bf16x8 hsl = {0,0,0,0,0,0,0,0};      // lo
    f32x4 cba, cbb;                      // bias C-frags (rows 4g+i, 16+4g+i)

    if (wv == 0) {
        load_wfrag(W_ih0,  0, n, g, WIhi0, WIlo0);
        load_wfrag(W_ih0, 16, n, g, WIhi1, WIlo1);
        load_wfrag(W_hh0,  0, n, g, WHhi0, WHlo0);
        load_wfrag(W_hh0, 16, n, g, WHhi1, WHlo1);
#pragma unroll
        for (int i = 0; i < 4; ++i) {
            cba[i] = b_ih0[4*g + i]      + b_hh0[4*g + i];
            cbb[i] = b_ih0[16 + 4*g + i] + b_hh0[16 + 4*g + i];
        }
    } else {
        load_wfrag(W_ih1,  0, n, g, WIhi0, WIlo0);
        load_wfrag(W_ih1, 16, n, g, WIhi1, WIlo1);
        load_wfrag(W_hh1,  0, n, g, WHhi0, WHlo0);
        load_wfrag(W_hh1, 16, n, g, WHhi1, WHlo1);
#pragma unroll
        for (int i = 0; i < 4; ++i) {
            cba[i] = b_ih1[4*g + i]      + b_hh1[4*g + i];
            cbb[i] = b_ih1[16 + 4*g + i] + b_hh1[16 + 4*g + i];
        }
    }

    // x stream: lane (n,g) loads x[batch][t][4g..4g+3] and [16+4g..16+4g+3]
    const float* xbase = x + (size_t)(blockIdx.x*16 + n) * (RT*RH) + 4*g;
    float4 xa0, xb0, xa1, xb1, xa2, xb2, xa3, xb3;

#define PREF(XA, XB, TP) do { \
    int tp_ = (TP); if (tp_ > RT-1) tp_ = RT-1; \
    const float* p_ = xbase + tp_*RH; \
    XA = *(const float4*)(p_); \
    XB = *(const float4*)(p_ + 16); \
} while (0)

#define TANH4(dst, dv) do { dst[0]=fast_tanh(dv[0]); dst[1]=fast_tanh(dv[1]); \
                            dst[2]=fast_tanh(dv[2]); dst[3]=fast_tanh(dv[3]); } while(0)

#define PACKH(t0_, t1_) do { \
    _Pragma("unroll") \
    for (int e_ = 0; e_ < 8; ++e_) { \
        float v_ = (e_ < 4) ? t0_[e_ & 3] : t1_[e_ & 3]; \
        unsigned short hb_ = f2bf(v_); \
        hsh[e_] = (short)hb_; \
        hsl[e_] = (short)f2bf(v_ - bf2f(hb_)); \
    } \
} while (0)

#define ASTEP(T_, XA, XB, WSL, DOPREF) do { \
    bf16x8 xf_; \
    xf_[0]=(short)f2bf(XA.x); xf_[1]=(short)f2bf(XA.y); \
    xf_[2]=(short)f2bf(XA.z); xf_[3]=(short)f2bf(XA.w); \
    xf_[4]=(short)f2bf(XB.x); xf_[5]=(short)f2bf(XB.y); \
    xf_[6]=(short)f2bf(XB.z); xf_[7]=(short)f2bf(XB.w); \
    if (DOPREF) { PREF(XA, XB, (T_) + 4); } \
    f32x4 d0_, d1_; \
    d0_ = MFMA(WIhi0, xf_, cba);  d1_ = MFMA(WIhi1, xf_, cbb); \
    d0_ = MFMA(WIlo0, xf_, d0_);  d1_ = MFMA(WIlo1, xf_, d1_); \
    d0_ = MFMA(WHhi0, hsh, d0_);  d1_ = MFMA(WHhi1, hsh, d1_); \
    d0_ = MFMA(WHhi0, hsl, d0_);  d1_ = MFMA(WHhi1, hsl, d1_); \
    d0_ = MFMA(WHlo0, hsh, d0_);  d1_ = MFMA(WHlo1, hsh, d1_); \
    float t0_[4], t1_[4]; TANH4(t0_, d0_); TANH4(t1_, d1_); \
    PACKH(t0_, t1_); \
    *(bf16x8*)&hslab[WSL][0][ln][0] = hsh; \
    *(bf16x8*)&hslab[WSL][1][ln][0] = hsl; \
} while (0)

#define BSTEP(RSL, FIN) do { \
    bf16x8 rhi_ = *(const bf16x8*)&hslab[RSL][0][ln][0]; \
    bf16x8 rlo_ = *(const bf16x8*)&hslab[RSL][1][ln][0]; \
    f32x4 d0_, d1_; \
    d0_ = MFMA(WIhi0, rhi_, cba);  d1_ = MFMA(WIhi1, rhi_, cbb); \
    d0_ = MFMA(WIhi0, rlo_, d0_);  d1_ = MFMA(WIhi1, rlo_, d1_); \
    d0_ = MFMA(WIlo0, rhi_, d0_);  d1_ = MFMA(WIlo1, rhi_, d1_); \
    d0_ = MFMA(WHhi0, hsh, d0_);   d1_ = MFMA(WHhi1, hsh, d1_); \
    d0_ = MFMA(WHhi0, hsl, d0_);   d1_ = MFMA(WHhi1, hsl, d1_); \
    d0_ = MFMA(WHlo0, hsh, d0_);   d1_ = MFMA(WHlo1, hsh, d1_); \
    float t0_[4], t1_[4]; TANH4(t0_, d0_); TANH4(t1_, d1_); \
    if (FIN) { \
        f32x4 o0_, o1_; \
        o0_[0]=t0_[0]; o0_[1]=t0_[1]; o0_[2]=t0_[2]; o0_[3]=t0_[3]; \
        o1_[0]=t1_[0]; o1_[1]=t1_[1]; o1_[2]=t1_[2]; o1_[3]=t1_[3]; \
        *(f32x4*)&h2fin[n][4*g]      = o0_; \
        *(f32x4*)&h2fin[n][16 + 4*g] = o1_; \
    } else { \
        PACKH(t0_, t1_); \
    } \
} while (0)

    if (wv == 0) {
        PREF(xa0, xb0, 0); PREF(xa1, xb1, 1);
        PREF(xa2, xb2, 2); PREF(xa3, xb3, 3);
        ASTEP(0, xa0, xb0, 0, 1);        // h1(0), h-terms are exact zeros
    }
    __syncthreads();

    for (int k = 0; k < 511; ++k) {
        const int tb = 4*k;
        if (wv == 0) ASTEP(tb+1, xa1, xb1, 1, 1); else BSTEP(0, 0);
        __syncthreads();
        if (wv == 0) ASTEP(tb+2, xa2, xb2, 0, 1); else BSTEP(1, 0);
        __syncthreads();
        if (wv == 0) ASTEP(tb+3, xa3, xb3, 1, 1); else BSTEP(0, 0);
        __syncthreads();
        if (wv == 0) ASTEP(tb+4, xa0, xb0, 0, 1); else BSTEP(1, 0);
        __syncthreads();
    }
    // t = 2045, 2046, 2047 (A); h2(2044..2046) (B)
    if (wv == 0) ASTEP(2045, xa1, xb1, 1, 0); else BSTEP(0, 0);
    __syncthreads();
    if (wv == 0) ASTEP(2046, xa2, xb2, 0, 0); else BSTEP(1, 0);
    __syncthreads();
    if (wv == 0) ASTEP(2047, xa3, xb3, 1, 0); else BSTEP(0, 0);
    __syncthreads();

    if (wv == 1) {
        BSTEP(1, 1);                      // h2(2047) -> h2fin (f32)
        // FC epilogue: lane (n, g) covers classes {g, g+4, g+8}
        const int batch = blockIdx.x * 16 + n;
#pragma unroll
        for (int ci = 0; ci < 3; ++ci) {
            int cc = g + 4*ci;
            if (cc < RC) {
                float s = fc_b[cc];
#pragma unroll
                for (int kk = 0; kk < RH; ++kk)
                    s = fmaf(fc_w[cc*RH + kk], h2fin[n][kk], s);
                out[batch*RC + cc] = s;
            }
        }
    }
#undef PREF
#undef TANH4
#undef PACKH
#undef ASTEP
#undef BSTEP
}

extern "C" void kernel_launch(void* const* d_in, const int* in_sizes, int n_in,
                              void* d_out, int out_size, void* d_ws, size_t ws_size,
                              hipStream_t stream) {
    const float* x     = (const float*)d_in[0];
    const float* W_ih0 = (const float*)d_in[1];
    const float* W_hh0 = (const float*)d_in[2];
    const float* b_ih0 = (const float*)d_in[3];
    const float* b_hh0 = (const float*)d_in[4];
    const float* W_ih1 = (const float*)d_in[5];
    const float* W_hh1 = (const float*)d_in[6];
    const float* b_ih1 = (const float*)d_in[7];
    const float* b_hh1 = (const float*)d_in[8];
    const float* fc_w  = (const float*)d_in[9];
    const float* fc_b  = (const float*)d_in[10];
    float* out = (float*)d_out;

    rnn2_mfma_kernel<<<32, 128, 0, stream>>>(x, W_ih0, W_hh0, b_ih0, b_hh0,
                                             W_ih1, W_hh1, b_ih1, b_hh1,
                                             fc_w, fc_b, out);
}

// Round 5
// 622.315 us; speedup vs baseline: 1.4743x; 1.3879x over previous
//
#include <hip/hip_runtime.h>

#define RH 32
#define RT 2048
#define RC 10

typedef __attribute__((ext_vector_type(8))) _Float16 f16x8;
typedef __attribute__((ext_vector_type(4))) float f32x4;

#define MFMA16(a,b,c) __builtin_amdgcn_mfma_f32_16x16x32_f16((a),(b),(c),0,0,0)

// tanh(x) = 1 - 2/(exp(2x)+1); saturates correctly at +/-inf.
__device__ __forceinline__ float fast_tanh(float x) {
    float e = __builtin_amdgcn_exp2f(x * 2.88539008177792681472f);
    return fmaf(-2.0f, __builtin_amdgcn_rcpf(e + 1.0f), 1.0f);
}

// A-frag rows [base,base+16): lane(n,g) holds W[base+n][k], k = 4g+(e&3)+16*(e>>2)
// (layout validated in round 4: same mapping passed end-to-end with bf16)
__device__ __forceinline__ f16x8 load_wfrag16(const float* __restrict__ W,
                                              int base, int n, int g) {
    f16x8 f;
#pragma unroll
    for (int e = 0; e < 8; ++e) {
        int k = 4*g + (e & 3) + 16*(e >> 2);
        f[e] = (_Float16)W[(base + n)*RH + k];   // RNE
    }
    return f;
}

__global__ __launch_bounds__(64) void rnn2_mfma1w_kernel(
    const float* __restrict__ x,
    const float* __restrict__ W_ih0, const float* __restrict__ W_hh0,
    const float* __restrict__ b_ih0, const float* __restrict__ b_hh0,
    const float* __restrict__ W_ih1, const float* __restrict__ W_hh1,
    const float* __restrict__ b_ih1, const float* __restrict__ b_hh1,
    const float* __restrict__ fc_w, const float* __restrict__ fc_b,
    float* __restrict__ out)
{
    __shared__ float h2fin[16][RH];

    const int ln = threadIdx.x;      // single wave per block
    const int n  = ln & 15;          // batch column within 16-batch tile
    const int g  = ln >> 4;          // row/k 4-group

    // All 8 weight tile-fragments in registers (f16).
    f16x8 WI0a = load_wfrag16(W_ih0,  0, n, g);
    f16x8 WI0b = load_wfrag16(W_ih0, 16, n, g);
    f16x8 WH0a = load_wfrag16(W_hh0,  0, n, g);
    f16x8 WH0b = load_wfrag16(W_hh0, 16, n, g);
    f16x8 WI1a = load_wfrag16(W_ih1,  0, n, g);
    f16x8 WI1b = load_wfrag16(W_ih1, 16, n, g);
    f16x8 WH1a = load_wfrag16(W_hh1,  0, n, g);
    f16x8 WH1b = load_wfrag16(W_hh1, 16, n, g);

    f32x4 cb1a, cb1b, cb2a, cb2b;    // bias C-frags (rows 4g+i / 16+4g+i)
#pragma unroll
    for (int i = 0; i < 4; ++i) {
        cb1a[i] = b_ih0[4*g + i]      + b_hh0[4*g + i];
        cb1b[i] = b_ih0[16 + 4*g + i] + b_hh0[16 + 4*g + i];
        cb2a[i] = b_ih1[4*g + i]      + b_hh1[4*g + i];
        cb2b[i] = b_ih1[16 + 4*g + i] + b_hh1[16 + 4*g + i];
    }

    f16x8 h1f, h2f;                  // recurrent states (D-frag == next B-frag)
#pragma unroll
    for (int e = 0; e < 8; ++e) { h1f[e] = (_Float16)0.0f; h2f[e] = (_Float16)0.0f; }

    // x stream: lane (n,g) needs x[batch][t][4g..4g+3] and [16+4g..16+4g+3]
    const float* xp = x + (size_t)(blockIdx.x*16 + n) * (RT*RH) + 4*g;
    float4 A0, B0, A1, B1, A2, B2, A3, B3;   // 4-step register prefetch ring

#define PREF(A_, B_, T_) do { \
    const float* p_ = xp + (size_t)(T_) * RH; \
    A_ = *(const float4*)p_; \
    B_ = *(const float4*)(p_ + 16); \
} while (0)

#define STEP(A_, B_, DOPREF, PT_) do { \
    f16x8 xf_; \
    { \
        auto q0_ = __builtin_amdgcn_cvt_pkrtz(A_.x, A_.y); \
        auto q1_ = __builtin_amdgcn_cvt_pkrtz(A_.z, A_.w); \
        auto q2_ = __builtin_amdgcn_cvt_pkrtz(B_.x, B_.y); \
        auto q3_ = __builtin_amdgcn_cvt_pkrtz(B_.z, B_.w); \
        xf_[0] = q0_[0]; xf_[1] = q0_[1]; xf_[2] = q1_[0]; xf_[3] = q1_[1]; \
        xf_[4] = q2_[0]; xf_[5] = q2_[1]; xf_[6] = q3_[0]; xf_[7] = q3_[1]; \
    } \
    if (DOPREF) { PREF(A_, B_, PT_); } \
    f32x4 d0_ = MFMA16(WI0a, xf_, cb1a); \
    f32x4 d1_ = MFMA16(WI0b, xf_, cb1b); \
    d0_ = MFMA16(WH0a, h1f, d0_); \
    d1_ = MFMA16(WH0b, h1f, d1_); \
    _Pragma("unroll") \
    for (int i_ = 0; i_ < 4; ++i_) { d0_[i_] = fast_tanh(d0_[i_]); d1_[i_] = fast_tanh(d1_[i_]); } \
    _Pragma("unroll") \
    for (int i_ = 0; i_ < 4; ++i_) { h1f[i_] = (_Float16)d0_[i_]; h1f[4+i_] = (_Float16)d1_[i_]; } \
    f32x4 e0_ = MFMA16(WI1a, h1f, cb2a); \
    f32x4 e1_ = MFMA16(WI1b, h1f, cb2b); \
    e0_ = MFMA16(WH1a, h2f, e0_); \
    e1_ = MFMA16(WH1b, h2f, e1_); \
    _Pragma("unroll") \
    for (int i_ = 0; i_ < 4; ++i_) { e0_[i_] = fast_tanh(e0_[i_]); e1_[i_] = fast_tanh(e1_[i_]); } \
    _Pragma("unroll") \
    for (int i_ = 0; i_ < 4; ++i_) { h2f[i_] = (_Float16)e0_[i_]; h2f[4+i_] = (_Float16)e1_[i_]; } \
} while (0)

    PREF(A0, B0, 0); PREF(A1, B1, 1); PREF(A2, B2, 2); PREF(A3, B3, 3);

    for (int k = 0; k < 511; ++k) {
        const int tb = 4*k;
        STEP(A0, B0, 1, tb + 4);
        STEP(A1, B1, 1, tb + 5);
        STEP(A2, B2, 1, tb + 6);
        STEP(A3, B3, 1, tb + 7);
    }
    // t = 2044..2047, no prefetch
    STEP(A0, B0, 0, 0);
    STEP(A1, B1, 0, 0);
    STEP(A2, B2, 0, 0);
    STEP(A3, B3, 0, 0);
#undef STEP
#undef PREF

    // Final h2 -> LDS (f32), then FC epilogue across all 64 lanes.
#pragma unroll
    for (int i = 0; i < 4; ++i) {
        h2fin[n][4*g + i]      = (float)h2f[i];
        h2fin[n][16 + 4*g + i] = (float)h2f[4 + i];
    }
    __syncthreads();

    for (int c = ln; c < 16 * RC; c += 64) {
        const int bt = c / RC;
        const int cl = c % RC;
        float s = fc_b[cl];
#pragma unroll
        for (int kk = 0; kk < RH; ++kk)
            s = fmaf(fc_w[cl*RH + kk], h2fin[bt][kk], s);
        out[(size_t)(blockIdx.x*16 + bt) * RC + cl] = s;
    }
}

extern "C" void kernel_launch(void* const* d_in, const int* in_sizes, int n_in,
                              void* d_out, int out_size, void* d_ws, size_t ws_size,
                              hipStream_t stream) {
    const float* x     = (const float*)d_in[0];
    const float* W_ih0 = (const float*)d_in[1];
    const float* W_hh0 = (const float*)d_in[2];
    const float* b_ih0 = (const float*)d_in[3];
    const float* b_hh0 = (const float*)d_in[4];
    const float* W_ih1 = (const float*)d_in[5];
    const float* W_hh1 = (const float*)d_in[6];
    const float* b_ih1 = (const float*)d_in[7];
    const float* b_hh1 = (const float*)d_in[8];
    const float* fc_w  = (const float*)d_in[9];
    const float* fc_b  = (const float*)d_in[10];
    float* out = (float*)d_out;

    rnn2_mfma1w_kernel<<<32, 64, 0, stream>>>(x, W_ih0, W_hh0, b_ih0, b_hh0,
                                              W_ih1, W_hh1, b_ih1, b_hh1,
                                              fc_w, fc_b, out);
}